// Round 1
// baseline (75.607 us; speedup 1.0000x reference)
//
#include <hip/hip_runtime.h>
#include <hip/hip_bf16.h>

// Problem constants (from reference setup_inputs):
//   b=8, n=1024, m=2048, x_dim=1, Y_DIM=2 -> c=3, Z_DIM=128
constexpr int B  = 8;
constexpr int N  = 1024;
constexpr int M  = 2048;
constexpr int ZD = 128;
constexpr int JPB = 4;          // j-rows per block (one per wave, 256 thr = 4 waves)
constexpr float EPS = 1e-8f;
constexpr float LOG2E = 1.4426950408889634f;

__global__ __launch_bounds__(256) void encoder_fused(
    const float* __restrict__ x,      // (B, N, 1)
    const float* __restrict__ y,      // (B, N, 2)
    const float* __restrict__ t,      // (B, M, 1)
    const float* __restrict__ sigma,  // (3,)
    const float* __restrict__ W,      // (ZD, 3) row-major
    const float* __restrict__ bfc,    // (ZD,)
    float* __restrict__ out)          // (B, M, ZD)
{
    __shared__ float sx[N];
    __shared__ float sy1[N];
    __shared__ float sy2[N];

    const int blk = blockIdx.x;
    const int b   = blk / (M / JPB);
    const int jt  = blk % (M / JPB);
    const int tid = threadIdx.x;
    const int wave = tid >> 6;
    const int lane = tid & 63;

    // Stage x and y (SoA) for this batch into LDS. Coalesced float/float2 loads.
    for (int i = tid; i < N; i += 256) {
        sx[i] = x[b * N + i];
        float2 yv = reinterpret_cast<const float2*>(y)[b * N + i];
        sy1[i] = yv.x;
        sy2[i] = yv.y;
    }
    __syncthreads();

    // Per-channel exponent multiplier: q_c = -0.5 * log2(e) * exp(-2*sigma_c)
    // so kernel_c(d) = exp2(d*d * q_c) == exp(-0.5 * (d/scale_c)^2).
    const float q0 = -0.5f * LOG2E * __builtin_amdgcn_exp2f(-2.0f * sigma[0] * LOG2E);
    const float q1 = -0.5f * LOG2E * __builtin_amdgcn_exp2f(-2.0f * sigma[1] * LOG2E);
    const float q2 = -0.5f * LOG2E * __builtin_amdgcn_exp2f(-2.0f * sigma[2] * LOG2E);

    const int j = jt * JPB + wave;
    const float tj = t[b * M + j];

    float z0 = 0.f, z1 = 0.f, z2 = 0.f;
#pragma unroll
    for (int k = 0; k < N / 64; ++k) {
        const int i = k * 64 + lane;
        const float d  = tj - sx[i];
        const float d2 = d * d;
        const float e0 = __builtin_amdgcn_exp2f(d2 * q0);
        const float e1 = __builtin_amdgcn_exp2f(d2 * q1);
        const float e2 = __builtin_amdgcn_exp2f(d2 * q2);
        z0 += e0;
        z1 = fmaf(sy1[i], e1, z1);
        z2 = fmaf(sy2[i], e2, z2);
    }

    // Wave-wide butterfly reduction (all lanes end with the full sums).
#pragma unroll
    for (int off = 32; off; off >>= 1) {
        z0 += __shfl_xor(z0, off);
        z1 += __shfl_xor(z1, off);
        z2 += __shfl_xor(z2, off);
    }

    const float inv = 1.0f / (z0 + EPS);
    const float a1 = z1 * inv;
    const float a2 = z2 * inv;

    // Each lane produces 2 of the 128 outputs for this (b, j).
    const int k0 = lane * 2;
    const float o0 = fmaf(z0, W[k0 * 3 + 0],
                     fmaf(a1, W[k0 * 3 + 1],
                     fmaf(a2, W[k0 * 3 + 2], bfc[k0])));
    const float o1 = fmaf(z0, W[(k0 + 1) * 3 + 0],
                     fmaf(a1, W[(k0 + 1) * 3 + 1],
                     fmaf(a2, W[(k0 + 1) * 3 + 2], bfc[k0 + 1])));

    reinterpret_cast<float2*>(out)[(size_t)(b * M + j) * (ZD / 2) + lane] =
        make_float2(o0, o1);
}

extern "C" void kernel_launch(void* const* d_in, const int* in_sizes, int n_in,
                              void* d_out, int out_size, void* d_ws, size_t ws_size,
                              hipStream_t stream) {
    const float* x     = (const float*)d_in[0];
    const float* y     = (const float*)d_in[1];
    const float* t     = (const float*)d_in[2];
    const float* sigma = (const float*)d_in[3];
    const float* W     = (const float*)d_in[4];
    const float* bfc   = (const float*)d_in[5];
    float* out = (float*)d_out;

    dim3 grid(B * (M / JPB));   // 8 * 512 = 4096 blocks
    encoder_fused<<<grid, 256, 0, stream>>>(x, y, t, sigma, W, bfc, out);
}

// Round 2
// 72.117 us; speedup vs baseline: 1.0484x; 1.0484x over previous
//
#include <hip/hip_runtime.h>
#include <hip/hip_bf16.h>

// Problem constants (from reference setup_inputs):
//   b=8, n=1024, m=2048, x_dim=1, Y_DIM=2 -> c=3, Z_DIM=128
constexpr int B  = 8;
constexpr int N  = 1024;
constexpr int M  = 2048;
constexpr int ZD = 128;
constexpr int JPW = 2;           // j-rows per wave
constexpr int JPB = 4 * JPW;     // j-rows per block (4 waves/block)
constexpr float EPS = 1e-8f;
constexpr float LOG2E = 1.4426950408889634f;

__global__ __launch_bounds__(256, 8) void encoder_fused(
    const float* __restrict__ x,      // (B, N, 1)
    const float* __restrict__ y,      // (B, N, 2)
    const float* __restrict__ t,      // (B, M, 1)
    const float* __restrict__ sigma,  // (3,)
    const float* __restrict__ W,      // (ZD, 3) row-major
    const float* __restrict__ bfc,    // (ZD,)
    float* __restrict__ out)          // (B, M, ZD)
{
    __shared__ float sx[N];
    __shared__ float sy1[N];
    __shared__ float sy2[N];

    const int blk  = blockIdx.x;
    const int b    = blk / (M / JPB);
    const int jt   = blk % (M / JPB);
    const int tid  = threadIdx.x;
    const int wave = tid >> 6;
    const int lane = tid & 63;

    // Stage x and y (SoA) for this batch into LDS. Coalesced loads.
    for (int i = tid; i < N; i += 256) {
        sx[i] = x[b * N + i];
        float2 yv = reinterpret_cast<const float2*>(y)[b * N + i];
        sy1[i] = yv.x;
        sy2[i] = yv.y;
    }
    __syncthreads();

    const float s0 = sigma[0], s1 = sigma[1], s2 = sigma[2];
    // q_c = -0.5 * log2(e) * exp(-2*sigma_c):  kernel_c(d) = exp2(d*d*q_c)
    const float q0 = -0.5f * LOG2E * __builtin_amdgcn_exp2f(-2.0f * s0 * LOG2E);
    const float q1 = -0.5f * LOG2E * __builtin_amdgcn_exp2f(-2.0f * s1 * LOG2E);
    const float q2 = -0.5f * LOG2E * __builtin_amdgcn_exp2f(-2.0f * s2 * LOG2E);

    const int j0 = jt * JPB + wave * JPW;      // this wave's two j-rows
    const float ta = t[b * M + j0];
    const float tb = t[b * M + j0 + 1];

    float z0a = 0.f, z1a = 0.f, z2a = 0.f;
    float z0b = 0.f, z1b = 0.f, z2b = 0.f;

    if (s0 == s1 && s1 == s2) {
        // Fast path (holds for the actual data, sigma == 0): one exp serves
        // all three channels since the scales are identical.
#pragma unroll
        for (int k = 0; k < N / 64; ++k) {
            const int i = k * 64 + lane;
            const float xi = sx[i], y1 = sy1[i], y2 = sy2[i];
            const float da = ta - xi, db = tb - xi;
            const float ea = __builtin_amdgcn_exp2f(da * da * q0);
            const float eb = __builtin_amdgcn_exp2f(db * db * q0);
            z0a += ea;  z1a = fmaf(y1, ea, z1a);  z2a = fmaf(y2, ea, z2a);
            z0b += eb;  z1b = fmaf(y1, eb, z1b);  z2b = fmaf(y2, eb, z2b);
        }
    } else {
        // General path: per-channel scales.
#pragma unroll
        for (int k = 0; k < N / 64; ++k) {
            const int i = k * 64 + lane;
            const float xi = sx[i], y1 = sy1[i], y2 = sy2[i];
            const float da = ta - xi, db = tb - xi;
            const float da2 = da * da, db2 = db * db;
            z0a += __builtin_amdgcn_exp2f(da2 * q0);
            z1a = fmaf(y1, __builtin_amdgcn_exp2f(da2 * q1), z1a);
            z2a = fmaf(y2, __builtin_amdgcn_exp2f(da2 * q2), z2a);
            z0b += __builtin_amdgcn_exp2f(db2 * q0);
            z1b = fmaf(y1, __builtin_amdgcn_exp2f(db2 * q1), z1b);
            z2b = fmaf(y2, __builtin_amdgcn_exp2f(db2 * q2), z2b);
        }
    }

    // Wave-wide butterfly reductions (all lanes end with the full sums).
#pragma unroll
    for (int off = 32; off; off >>= 1) {
        z0a += __shfl_xor(z0a, off);
        z1a += __shfl_xor(z1a, off);
        z2a += __shfl_xor(z2a, off);
        z0b += __shfl_xor(z0b, off);
        z1b += __shfl_xor(z1b, off);
        z2b += __shfl_xor(z2b, off);
    }

    const float inva = 1.0f / (z0a + EPS);
    const float a1 = z1a * inva, a2 = z2a * inva;
    const float invb = 1.0f / (z0b + EPS);
    const float b1 = z1b * invb, b2 = z2b * invb;

    // Each lane produces 2 of the 128 outputs for each of the 2 j-rows.
    const int k0 = lane * 2;
    const float w00 = W[k0 * 3 + 0], w01 = W[k0 * 3 + 1], w02 = W[k0 * 3 + 2];
    const float w10 = W[(k0 + 1) * 3 + 0], w11 = W[(k0 + 1) * 3 + 1], w12 = W[(k0 + 1) * 3 + 2];
    const float bf0 = bfc[k0], bf1 = bfc[k0 + 1];

    float2 oa, ob;
    oa.x = fmaf(z0a, w00, fmaf(a1, w01, fmaf(a2, w02, bf0)));
    oa.y = fmaf(z0a, w10, fmaf(a1, w11, fmaf(a2, w12, bf1)));
    ob.x = fmaf(z0b, w00, fmaf(b1, w01, fmaf(b2, w02, bf0)));
    ob.y = fmaf(z0b, w10, fmaf(b1, w11, fmaf(b2, w12, bf1)));

    reinterpret_cast<float2*>(out)[(size_t)(b * M + j0) * (ZD / 2) + lane]       = oa;
    reinterpret_cast<float2*>(out)[(size_t)(b * M + j0 + 1) * (ZD / 2) + lane]   = ob;
}

extern "C" void kernel_launch(void* const* d_in, const int* in_sizes, int n_in,
                              void* d_out, int out_size, void* d_ws, size_t ws_size,
                              hipStream_t stream) {
    const float* x     = (const float*)d_in[0];
    const float* y     = (const float*)d_in[1];
    const float* t     = (const float*)d_in[2];
    const float* sigma = (const float*)d_in[3];
    const float* W     = (const float*)d_in[4];
    const float* bfc   = (const float*)d_in[5];
    float* out = (float*)d_out;

    dim3 grid(B * (M / JPB));   // 8 * 256 = 2048 blocks, one full-occupancy pass
    encoder_fused<<<grid, 256, 0, stream>>>(x, y, t, sigma, W, bfc, out);
}